// Round 3
// baseline (35.803 us; speedup 1.0000x reference)
//
#include <hip/hip_runtime.h>

constexpr int TPB = 256;
constexpr int ROWS = 2;                       // rows per thread
constexpr int RPB = TPB * ROWS;               // 512 rows per block
constexpr int F4_PER_BLOCK = RPB * 13 / 4;    // 1664
constexpr int F4_FULL_ITERS = F4_PER_BLOCK / TPB;          // 6
constexpr int F4_REM = F4_PER_BLOCK - F4_FULL_ITERS * TPB; // 128

__global__ __launch_bounds__(TPB) void attctl_kernel(
    const float* __restrict__ rs,        // [n,13] root_state
    const float4* __restrict__ ct,       // [n,4]  control_target
    const float* __restrict__ mass_p,    // [1]
    const float* __restrict__ g_p,       // [1]
    const float* __restrict__ mixer,     // [4,4] row-major
    const float* __restrict__ max_thr,   // [4]
    const float* __restrict__ g_att,     // [3]
    const float* __restrict__ g_rate,    // [3]
    float4* __restrict__ out,            // [n,4]
    int n)
{
    __shared__ float s[RPB * 13];
    const int t = threadIdx.x;
    const long long bstart = (long long)blockIdx.x * RPB;
    const long long gbase = bstart * 13;

    const long long row0 = bstart + t;
    const long long row1 = bstart + TPB + t;

    // Hoist the independent control_target loads so their latency hides
    // under the staging loop.
    float4 c0 = make_float4(0.f, 0.f, 0.f, 0.f);
    float4 c1 = make_float4(0.f, 0.f, 0.f, 0.f);
    if (row0 < n) c0 = ct[row0];
    if (row1 < n) c1 = ct[row1];

    if (blockIdx.x != gridDim.x - 1) {
        // Full block: contiguous 16B-aligned span of 1664 float4.
        float4* s4 = (float4*)s;
        const float4* src4 = (const float4*)(rs + gbase);
        #pragma unroll
        for (int k = 0; k < F4_FULL_ITERS; ++k)
            s4[t + k * TPB] = src4[t + k * TPB];
        if (t < F4_REM)
            s4[t + F4_FULL_ITERS * TPB] = src4[t + F4_FULL_ITERS * TPB];
    } else {
        // Last block: scalar guarded path (handles any n).
        const long long total = (long long)n * 13;
        #pragma unroll
        for (int k = 0; k < 13 * ROWS; ++k) {
            long long gi = gbase + t + k * TPB;
            s[t + k * TPB] = (gi < total) ? rs[gi] : 0.0f;
        }
    }
    __syncthreads();

    // Wave-uniform small constants (scalar loads).
    const float ga0 = g_att[0], ga1 = g_att[1];
    const float gr0 = g_rate[0], gr1 = g_rate[1], gr2 = g_rate[2];
    const float mg = mass_p[0] * g_p[0];
    const float inv0 = 2.0f / max_thr[0];
    const float inv1 = 2.0f / max_thr[1];
    const float inv2 = 2.0f / max_thr[2];
    const float inv3 = 2.0f / max_thr[3];

    #pragma unroll
    for (int r = 0; r < ROWS; ++r) {
        const long long row = (r == 0) ? row0 : row1;
        if (row >= n) continue;
        const float4 c = (r == 0) ? c0 : c1;
        const float* q = &s[(t + r * TPB) * 13];

        const float w = q[3], x = q[4], y = q[5], z = q[6];
        const float avx = q[10], avy = q[11], avz = q[12];

        const float roll = c.x, pitch = c.y, yawr = c.z, thr_in = c.w;

        const float sr = __sinf(roll),  cr = __cosf(roll);
        const float sp = __sinf(pitch), cp = __cosf(pitch);
        const float sy = __sinf(yawr),  cy = __cosf(yawr);

        // quaternion -> R (pre-normalized)
        const float xx = x*x, yy = y*y, zz = z*z;
        const float xy = x*y, xz = x*z, yz = y*z;
        const float wx = w*x, wy = w*y, wz = w*z;
        const float r00 = 1.f - 2.f*(yy+zz), r01 = 2.f*(xy-wz),       r02 = 2.f*(xz+wy);
        const float r10 = 2.f*(xy+wz),       r11 = 1.f - 2.f*(xx+zz), r12 = 2.f*(yz-wx);
        const float r20 = 2.f*(xz-wy),       r21 = 2.f*(yz+wx),       r22 = 1.f - 2.f*(xx+yy);

        // R_des = Rz(yawr) * Rx(roll) * Ry(pitch)
        const float d00 = cy*cp - sy*sr*sp;
        const float d01 = -sy*cr;
        const float d02 = cy*sp + sy*sr*cp;
        const float d10 = sy*cp + cy*sr*sp;
        const float d11 = cy*cr;
        const float d12 = sy*sp - cy*sr*cp;
        const float d20 = -cr*sp;
        const float d21 = sr;
        const float d22 = cr*cp;

        // M = R_des^T @ R ; only 5 entries needed.
        const float M02 = d00*r02 + d10*r12 + d20*r22;
        const float M20 = d02*r00 + d12*r10 + d22*r20;
        const float M12 = d01*r02 + d11*r12 + d21*r22;
        const float M21 = d02*r01 + d12*r11 + d22*r21;
        const float M22 = d02*r02 + d12*r12 + d22*r22;

        const float ae0 = 0.5f*(M21 - M12);
        const float ae1 = 0.5f*(M02 - M20);

        const float re0 = avx - M02*yawr;
        const float re1 = avy - M12*yawr;
        const float re2 = avz - M22*yawr;

        const float a0 = -ae0*ga0 - re0*gr0;
        const float a1 = -ae1*ga1 - re1*gr1;
        const float a2 = -re2*gr2;
        const float th = thr_in * mg;

        float4 o;
        o.x = (a0*mixer[0]  + a1*mixer[1]  + a2*mixer[2]  + th*mixer[3])  * inv0 - 1.f;
        o.y = (a0*mixer[4]  + a1*mixer[5]  + a2*mixer[6]  + th*mixer[7])  * inv1 - 1.f;
        o.z = (a0*mixer[8]  + a1*mixer[9]  + a2*mixer[10] + th*mixer[11]) * inv2 - 1.f;
        o.w = (a0*mixer[12] + a1*mixer[13] + a2*mixer[14] + th*mixer[15]) * inv3 - 1.f;
        out[row] = o;
    }
}

extern "C" void kernel_launch(void* const* d_in, const int* in_sizes, int n_in,
                              void* d_out, int out_size, void* d_ws, size_t ws_size,
                              hipStream_t stream) {
    const float*  rs    = (const float*)d_in[0];
    const float4* ctrl  = (const float4*)d_in[1];
    const float*  mass  = (const float*)d_in[2];
    const float*  g     = (const float*)d_in[3];
    const float*  mixer = (const float*)d_in[4];
    const float*  mt    = (const float*)d_in[5];
    const float*  ga    = (const float*)d_in[6];
    const float*  gr    = (const float*)d_in[7];
    float4* out = (float4*)d_out;

    const int n = in_sizes[0] / 13;
    const int blocks = (n + RPB - 1) / RPB;
    hipLaunchKernelGGL(attctl_kernel, dim3(blocks), dim3(TPB), 0, stream,
                       rs, ctrl, mass, g, mixer, mt, ga, gr, out, n);
}

// Round 4
// 29.672 us; speedup vs baseline: 1.2066x; 1.2066x over previous
//
#include <hip/hip_runtime.h>

constexpr int TPB = 256;

__global__ __launch_bounds__(TPB) void attctl_kernel(
    const float* __restrict__ rs,        // [n,13] root_state
    const float4* __restrict__ ct,       // [n,4]  control_target
    const float* __restrict__ mass_p,    // [1]
    const float* __restrict__ g_p,       // [1]
    const float* __restrict__ mixer,     // [4,4] row-major
    const float* __restrict__ max_thr,   // [4]
    const float* __restrict__ g_att,     // [3]
    const float* __restrict__ g_rate,    // [3]
    float4* __restrict__ out,            // [n,4]
    int n)
{
    const long long row = (long long)blockIdx.x * TPB + threadIdx.x;
    if (row >= n) return;

    const float* rowp = rs + row * 13;
    // Dword-aligned vector loads of exactly the needed fields.
    // bytes 12..27: quat (w,x,y,z); bytes 36..51: (pad, wx, wy, wz)
    const float4 qv = *reinterpret_cast<const float4*>(rowp + 3);
    const float4 av = *reinterpret_cast<const float4*>(rowp + 9);
    const float4 c  = ct[row];

    const float w = qv.x, x = qv.y, y = qv.z, z = qv.w;
    const float avx = av.y, avy = av.z, avz = av.w;
    const float roll = c.x, pitch = c.y, yawr = c.z, thr_in = c.w;

    const float sr = __sinf(roll),  cr = __cosf(roll);
    const float sp = __sinf(pitch), cp = __cosf(pitch);
    const float sy = __sinf(yawr),  cy = __cosf(yawr);

    // quaternion -> R (pre-normalized)
    const float xx = x*x, yy = y*y, zz = z*z;
    const float xy = x*y, xz = x*z, yz = y*z;
    const float wx = w*x, wy = w*y, wz = w*z;
    const float r00 = 1.f - 2.f*(yy+zz), r01 = 2.f*(xy-wz),       r02 = 2.f*(xz+wy);
    const float r10 = 2.f*(xy+wz),       r11 = 1.f - 2.f*(xx+zz), r12 = 2.f*(yz-wx);
    const float r20 = 2.f*(xz-wy),       r21 = 2.f*(yz+wx),       r22 = 1.f - 2.f*(xx+yy);

    // R_des = Rz(yawr) * Rx(roll) * Ry(pitch)
    const float d00 = cy*cp - sy*sr*sp;
    const float d01 = -sy*cr;
    const float d02 = cy*sp + sy*sr*cp;
    const float d10 = sy*cp + cy*sr*sp;
    const float d11 = cy*cr;
    const float d12 = sy*sp - cy*sr*cp;
    const float d20 = -cr*sp;
    const float d21 = sr;
    const float d22 = cr*cp;

    // M = R_des^T @ R ; only 5 entries needed.
    const float M02 = d00*r02 + d10*r12 + d20*r22;
    const float M20 = d02*r00 + d12*r10 + d22*r20;
    const float M12 = d01*r02 + d11*r12 + d21*r22;
    const float M21 = d02*r01 + d12*r11 + d22*r21;
    const float M22 = d02*r02 + d12*r12 + d22*r22;

    const float ae0 = 0.5f*(M21 - M12);
    const float ae1 = 0.5f*(M02 - M20);
    // ae2 == 0; cross(ang_vel, ang_vel) == 0 exactly -> dropped

    const float re0 = avx - M02*yawr;
    const float re1 = avy - M12*yawr;
    const float re2 = avz - M22*yawr;

    const float ga0 = g_att[0], ga1 = g_att[1];
    const float gr0 = g_rate[0], gr1 = g_rate[1], gr2 = g_rate[2];

    const float a0 = -ae0*ga0 - re0*gr0;
    const float a1 = -ae1*ga1 - re1*gr1;
    const float a2 = -re2*gr2;
    const float th = thr_in * mass_p[0] * g_p[0];

    const float inv0 = 2.0f / max_thr[0];
    const float inv1 = 2.0f / max_thr[1];
    const float inv2 = 2.0f / max_thr[2];
    const float inv3 = 2.0f / max_thr[3];

    float4 o;
    o.x = (a0*mixer[0]  + a1*mixer[1]  + a2*mixer[2]  + th*mixer[3])  * inv0 - 1.f;
    o.y = (a0*mixer[4]  + a1*mixer[5]  + a2*mixer[6]  + th*mixer[7])  * inv1 - 1.f;
    o.z = (a0*mixer[8]  + a1*mixer[9]  + a2*mixer[10] + th*mixer[11]) * inv2 - 1.f;
    o.w = (a0*mixer[12] + a1*mixer[13] + a2*mixer[14] + th*mixer[15]) * inv3 - 1.f;
    out[row] = o;
}

extern "C" void kernel_launch(void* const* d_in, const int* in_sizes, int n_in,
                              void* d_out, int out_size, void* d_ws, size_t ws_size,
                              hipStream_t stream) {
    const float*  rs    = (const float*)d_in[0];
    const float4* ctrl  = (const float4*)d_in[1];
    const float*  mass  = (const float*)d_in[2];
    const float*  g     = (const float*)d_in[3];
    const float*  mixer = (const float*)d_in[4];
    const float*  mt    = (const float*)d_in[5];
    const float*  ga    = (const float*)d_in[6];
    const float*  gr    = (const float*)d_in[7];
    float4* out = (float4*)d_out;

    const int n = in_sizes[0] / 13;
    const int blocks = (n + TPB - 1) / TPB;
    hipLaunchKernelGGL(attctl_kernel, dim3(blocks), dim3(TPB), 0, stream,
                       rs, ctrl, mass, g, mixer, mt, ga, gr, out, n);
}